// Round 4
// baseline (259.581 us; speedup 1.0000x reference)
//
#include <hip/hip_runtime.h>
#include <cmath>

constexpr int N_ = 2;
constexpr int L_ = 2048;
constexpr int H_ = 16;
constexpr int E_ = 1024;
constexpr int ROWS_ = N_ * L_ * H_;   // 65536 token-head rows

typedef __attribute__((ext_vector_type(8))) short bf16x8;
typedef __attribute__((ext_vector_type(4))) float f32x4;
typedef unsigned short ushort_t;
#define MFMA16(a, b, c) __builtin_amdgcn_mfma_f32_16x16x32_bf16(a, b, c, 0, 0, 0)

__device__ __forceinline__ unsigned short f2bf(float x) {
    union { float f; unsigned u; } v; v.f = x;
    return (unsigned short)((v.u + 0x7fffu + ((v.u >> 16) & 1u)) >> 16);   // RNE
}
__device__ __forceinline__ unsigned pack2(float a, float b) {
    return (unsigned)f2bf(a) | ((unsigned)f2bf(b) << 16);
}

// ---------------------------------------------------------------------------
// Kernel 1: per-head projections, bf16 MFMA (unchanged from R3 — measured
// cheap). Emits q,k row-major [n][l][h][d]; v TRANSPOSED [n][h][d][l].
// ---------------------------------------------------------------------------
__global__ __launch_bounds__(256) void proj_kernel(
    const float* __restrict__ keys, const float* __restrict__ queries,
    const float* __restrict__ Wk, const float* __restrict__ Wq, const float* __restrict__ Wv,
    ushort_t* __restrict__ qo, ushort_t* __restrict__ ko, ushort_t* __restrict__ vto)
{
    constexpr int P = 72;
    __shared__ __align__(16) ushort_t Xq[64 * P];
    __shared__ __align__(16) ushort_t Xk[64 * P];
    __shared__ __align__(16) ushort_t Wqs[64 * P];
    __shared__ __align__(16) ushort_t Wks[64 * P];
    __shared__ __align__(16) ushort_t Wvs[64 * P];
    const int tid = threadIdx.x;
    const int lt = blockIdx.x & 31;
    const int h  = (blockIdx.x >> 5) & 15;
    const int n  = blockIdx.x >> 9;
    const int r0 = tid >> 4, c4 = (tid & 15) * 4;

#pragma unroll
    for (int j = 0; j < 4; ++j) {
        const int r = r0 + 16 * j;
        const size_t xoff = (size_t)(n * L_ + lt * 64 + r) * E_ + h * 64 + c4;
        const float4 xq = *(const float4*)&queries[xoff];
        const float4 xk = *(const float4*)&keys[xoff];
        const float4 wq = *(const float4*)&Wq[r * 64 + c4];
        const float4 wk = *(const float4*)&Wk[r * 64 + c4];
        const float4 wv = *(const float4*)&Wv[r * 64 + c4];
        *(uint2*)&Xq[r * P + c4]  = make_uint2(pack2(xq.x, xq.y), pack2(xq.z, xq.w));
        *(uint2*)&Xk[r * P + c4]  = make_uint2(pack2(xk.x, xk.y), pack2(xk.z, xk.w));
        *(uint2*)&Wqs[r * P + c4] = make_uint2(pack2(wq.x, wq.y), pack2(wq.z, wq.w));
        *(uint2*)&Wks[r * P + c4] = make_uint2(pack2(wk.x, wk.y), pack2(wk.z, wk.w));
        *(uint2*)&Wvs[r * P + c4] = make_uint2(pack2(wv.x, wv.y), pack2(wv.z, wv.w));
    }
    __syncthreads();

    const int wave = tid >> 6, lane = tid & 63;
    const int quad = lane >> 4, l16 = lane & 15;
    const int arow = (wave * 16 + l16) * P;
    const f32x4 zero = (f32x4){0.f, 0.f, 0.f, 0.f};

    bf16x8 a0 = *(const bf16x8*)&Xq[arow + quad * 8];
    bf16x8 a1 = *(const bf16x8*)&Xq[arow + 32 + quad * 8];
    bf16x8 c0 = *(const bf16x8*)&Xk[arow + quad * 8];
    bf16x8 c1 = *(const bf16x8*)&Xk[arow + 32 + quad * 8];
    f32x4 qf[4], kf[4];
#pragma unroll
    for (int nt = 0; nt < 4; ++nt) {
        const int brow = (nt * 16 + l16) * P;
        f32x4 acc = MFMA16(a0, *(const bf16x8*)&Wqs[brow + quad * 8], zero);
        qf[nt] = MFMA16(a1, *(const bf16x8*)&Wqs[brow + 32 + quad * 8], acc);
        acc = MFMA16(c0, *(const bf16x8*)&Wks[brow + quad * 8], zero);
        kf[nt] = MFMA16(c1, *(const bf16x8*)&Wks[brow + 32 + quad * 8], acc);
    }
    __syncthreads();

    const int crow = wave * 16 + quad * 4;
#pragma unroll
    for (int nt = 0; nt < 4; ++nt)
#pragma unroll
        for (int reg = 0; reg < 4; ++reg) {
            Xq[(crow + reg) * P + nt * 16 + l16]  = f2bf(qf[nt][reg]);
            Wqs[(crow + reg) * P + nt * 16 + l16] = f2bf(kf[nt][reg]);
        }
    asm volatile("s_waitcnt lgkmcnt(0)" ::: "memory");

    bf16x8 va0 = *(const bf16x8*)&Xq[arow + quad * 8];
    bf16x8 va1 = *(const bf16x8*)&Xq[arow + 32 + quad * 8];
    f32x4 vf[4];
#pragma unroll
    for (int nt = 0; nt < 4; ++nt) {
        const int brow = (nt * 16 + l16) * P;
        f32x4 acc = MFMA16(va0, *(const bf16x8*)&Wvs[brow + quad * 8], zero);
        vf[nt] = MFMA16(va1, *(const bf16x8*)&Wvs[brow + 32 + quad * 8], acc);
    }
#pragma unroll
    for (int nt = 0; nt < 4; ++nt)
#pragma unroll
        for (int reg = 0; reg < 4; ++reg)
            Xk[(nt * 16 + l16) * P + crow + reg] = f2bf(vf[nt][reg]);
    __syncthreads();

#pragma unroll
    for (int j = 0; j < 4; ++j) {
        const int r = r0 + 16 * j;
        const size_t qkoff = (size_t)(n * L_ + lt * 64 + r) * E_ + h * 64 + c4;
        *(uint2*)&qo[qkoff] = *(const uint2*)&Xq[r * P + c4];
        *(uint2*)&ko[qkoff] = *(const uint2*)&Wqs[r * P + c4];
        const size_t vtoff = ((size_t)(n * H_ + h) * 64 + r) * L_ + lt * 64 + c4;
        *(uint2*)&vto[vtoff] = *(const uint2*)&Xk[r * P + c4];
    }
}

// ---------------------------------------------------------------------------
// Kernel 2: flash attention, all-global fragments, no barriers.
// One WAVE per block; 32 q-rows (2 strips of 16). S^T = K*Q^T so both A(K)
// and B(Q) frags are 16B-contiguous global rows; V B-frags direct from
// vt[n][h][d][l]. Mask enters as MFMA C-init (0 / -1e9): p = exp2(s*log2e/32)
// gives exact 0 for masked keys (identical to reference semantics).
// LDS holds only the wave-private P round-trip (packed b64 writes).
// ---------------------------------------------------------------------------
__global__ __launch_bounds__(64, 2) void attn_kernel(
    const ushort_t* __restrict__ q, const ushort_t* __restrict__ k,
    const ushort_t* __restrict__ vt, const float* __restrict__ maskf,
    ushort_t* __restrict__ attn)
{
    constexpr int P = 72;
    constexpr float CEXP = 0.04508422002778010648f;   // log2(e)/32
    __shared__ __align__(16) ushort_t Ps[32 * P];
    __shared__ __align__(16) float Ls[32];

    const int b = blockIdx.x;
    const int qt = b & 63;           // 64 q-tiles of 32 rows
    const int h  = (b >> 6) & 15;
    const int n  = b >> 10;
    const int lane = threadIdx.x;
    const int l16 = lane & 15, quad = lane >> 4;

    const ushort_t* kh = k  + (size_t)n * L_ * E_ + h * 64;          // + key*E_ + d
    const ushort_t* vh = vt + (size_t)(n * H_ + h) * 64 * L_;        // + d*L_ + key
    const float*    mh = maskf + n * L_;
    const size_t qrow0 = (size_t)(n * L_ + qt * 32);

    // hoisted Q B-frags [strip][chain]
    bf16x8 qb[2][2];
#pragma unroll
    for (int s = 0; s < 2; ++s)
#pragma unroll
        for (int c = 0; c < 2; ++c)
            qb[s][c] = *(const bf16x8*)&q[(qrow0 + s * 16 + l16) * E_ + h * 64 + c * 32 + quad * 8];

    // tile-0 prefetch: K A-frags, mask C-init, V B-frags
    bf16x8 kr[4][2]; f32x4 mf[4]; bf16x8 vr[4][2];
#pragma unroll
    for (int mk = 0; mk < 4; ++mk) {
#pragma unroll
        for (int c = 0; c < 2; ++c)
            kr[mk][c] = *(const bf16x8*)&kh[(size_t)(mk * 16 + l16) * E_ + c * 32 + quad * 8];
        mf[mk] = *(const f32x4*)&mh[mk * 16 + quad * 4];
    }
#pragma unroll
    for (int dt = 0; dt < 4; ++dt)
#pragma unroll
        for (int c = 0; c < 2; ++c)
            vr[dt][c] = *(const bf16x8*)&vh[(size_t)(dt * 16 + l16) * L_ + c * 32 + quad * 8];

    float lacc[2] = {0.f, 0.f};
    f32x4 O[2][4];
#pragma unroll
    for (int s = 0; s < 2; ++s)
#pragma unroll
        for (int dt = 0; dt < 4; ++dt) O[s][dt] = (f32x4){0.f, 0.f, 0.f, 0.f};

    for (int t = 0; t < 32; ++t) {
        // S^T = K*Q^T + mask_init : C[key=quad*4+reg+16mk][q=l16]
        f32x4 sA[2][4];
#pragma unroll
        for (int s = 0; s < 2; ++s)
#pragma unroll
            for (int mk = 0; mk < 4; ++mk) {
                f32x4 acc = mf[mk];
                acc = MFMA16(kr[mk][0], qb[s][0], acc);
                sA[s][mk] = MFMA16(kr[mk][1], qb[s][1], acc);
            }

        // prefetch K/mask for t+1 (in flight during softmax+PV)
        const int tn = (t < 31) ? t + 1 : 31;
#pragma unroll
        for (int mk = 0; mk < 4; ++mk) {
#pragma unroll
            for (int c = 0; c < 2; ++c)
                kr[mk][c] = *(const bf16x8*)&kh[(size_t)(tn * 64 + mk * 16 + l16) * E_ + c * 32 + quad * 8];
            mf[mk] = *(const f32x4*)&mh[tn * 64 + mk * 16 + quad * 4];
        }

        // p = exp2(s*CEXP)  (masked rows carry -1e9 from C-init -> exact 0)
#pragma unroll
        for (int s = 0; s < 2; ++s)
#pragma unroll
            for (int mk = 0; mk < 4; ++mk) {
                const float p0 = __builtin_amdgcn_exp2f(sA[s][mk][0] * CEXP);
                const float p1 = __builtin_amdgcn_exp2f(sA[s][mk][1] * CEXP);
                const float p2 = __builtin_amdgcn_exp2f(sA[s][mk][2] * CEXP);
                const float p3 = __builtin_amdgcn_exp2f(sA[s][mk][3] * CEXP);
                lacc[s] += (p0 + p1) + (p2 + p3);
                *(uint2*)&Ps[(s * 16 + l16) * P + mk * 16 + quad * 4] =
                    make_uint2(pack2(p0, p1), pack2(p2, p3));
            }
        asm volatile("s_waitcnt lgkmcnt(0)" ::: "memory");   // wave-local P

        // O += P*V  (A = P rows, B = V direct-global)
        bf16x8 pa[2][2];
#pragma unroll
        for (int s = 0; s < 2; ++s)
#pragma unroll
            for (int c = 0; c < 2; ++c)
                pa[s][c] = *(const bf16x8*)&Ps[(s * 16 + l16) * P + c * 32 + quad * 8];
#pragma unroll
        for (int s = 0; s < 2; ++s)
#pragma unroll
            for (int dt = 0; dt < 4; ++dt) {
                O[s][dt] = MFMA16(pa[s][0], vr[dt][0], O[s][dt]);
                O[s][dt] = MFMA16(pa[s][1], vr[dt][1], O[s][dt]);
            }

        // prefetch V for t+1 (regs free after PV)
#pragma unroll
        for (int dt = 0; dt < 4; ++dt)
#pragma unroll
            for (int c = 0; c < 2; ++c)
                vr[dt][c] = *(const bf16x8*)&vh[(size_t)(dt * 16 + l16) * L_ + tn * 64 + c * 32 + quad * 8];
    }

    // l reduction (per q=l16, partial over quad) and distribution
#pragma unroll
    for (int s = 0; s < 2; ++s) {
        float v = lacc[s];
        v += __shfl_xor(v, 16);
        v += __shfl_xor(v, 32);
        if (quad == 0) Ls[s * 16 + l16] = 1.f / v;
    }
    asm volatile("s_waitcnt lgkmcnt(0)" ::: "memory");
    f32x4 linv[2];
#pragma unroll
    for (int s = 0; s < 2; ++s) linv[s] = *(const f32x4*)&Ls[s * 16 + quad * 4];

#pragma unroll
    for (int s = 0; s < 2; ++s)
#pragma unroll
        for (int dt = 0; dt < 4; ++dt)
#pragma unroll
            for (int reg = 0; reg < 4; ++reg) {
                const size_t row = qrow0 + s * 16 + quad * 4 + reg;
                attn[row * E_ + h * 64 + dt * 16 + l16] = f2bf(O[s][dt][reg] * linv[s][reg]);
            }
}

// ---------------------------------------------------------------------------
// Kernel 3: Wo fp32 -> bf16, and mask -> maskf (0 / -1e9)
// ---------------------------------------------------------------------------
__global__ __launch_bounds__(256) void conv_misc_kernel(
    const float* __restrict__ Wo, const int* __restrict__ mask,
    ushort_t* __restrict__ Wob, float* __restrict__ maskf)
{
    if (blockIdx.x < 1024) {
        const int i = (blockIdx.x * 256 + threadIdx.x) * 4;
        const float4 w = *(const float4*)&Wo[i];
        *(uint2*)&Wob[i] = make_uint2(pack2(w.x, w.y), pack2(w.z, w.w));
    } else {
        const int j = (blockIdx.x - 1024) * 256 + threadIdx.x;
        if (j < N_ * L_) maskf[j] = mask[j] ? 0.f : -1e9f;
    }
}

// ---------------------------------------------------------------------------
// Kernel 4: out = attn(4096x1024) @ Wo^T + bo. 128x64 tiles, 2-strip waves
// (32 rows x 64 cols per wave, B-frags shared across strips).
// ---------------------------------------------------------------------------
__global__ __launch_bounds__(256) void outproj_kernel(
    const ushort_t* __restrict__ attn, const ushort_t* __restrict__ Wob,
    const float* __restrict__ bo, float* __restrict__ out)
{
    constexpr int P = 72;
    __shared__ __align__(16) ushort_t As[128 * P];
    __shared__ __align__(16) ushort_t Bs[64 * P];
    const int tid = threadIdx.x;
    const int bc = (blockIdx.x & 15) * 64;
    const int br = (blockIdx.x >> 4) * 128;
    const int r0 = tid >> 4, c4 = (tid & 15) * 4;
    const int wave = tid >> 6, lane = tid & 63;
    const int quad = lane >> 4, l16 = lane & 15;

    uint2 ar[8], brg[4];
#pragma unroll
    for (int j = 0; j < 8; ++j)
        ar[j] = *(const uint2*)&attn[(size_t)(br + r0 + 16 * j) * E_ + c4];
#pragma unroll
    for (int j = 0; j < 4; ++j)
        brg[j] = *(const uint2*)&Wob[(size_t)(bc + r0 + 16 * j) * E_ + c4];

    f32x4 acc[2][4];
#pragma unroll
    for (int s = 0; s < 2; ++s)
#pragma unroll
        for (int nt = 0; nt < 4; ++nt) acc[s][nt] = (f32x4){0.f, 0.f, 0.f, 0.f};

    for (int kt = 0; kt < 16; ++kt) {
#pragma unroll
        for (int j = 0; j < 8; ++j) *(uint2*)&As[(r0 + 16 * j) * P + c4] = ar[j];
#pragma unroll
        for (int j = 0; j < 4; ++j) *(uint2*)&Bs[(r0 + 16 * j) * P + c4] = brg[j];
        __syncthreads();
        const int knext = ((kt < 15) ? (kt + 1) : kt) * 64;
#pragma unroll
        for (int j = 0; j < 8; ++j)
            ar[j] = *(const uint2*)&attn[(size_t)(br + r0 + 16 * j) * E_ + knext + c4];
#pragma unroll
        for (int j = 0; j < 4; ++j)
            brg[j] = *(const uint2*)&Wob[(size_t)(bc + r0 + 16 * j) * E_ + knext + c4];

        bf16x8 aw[2][2], bw[4][2];
#pragma unroll
        for (int s = 0; s < 2; ++s)
#pragma unroll
            for (int c = 0; c < 2; ++c)
                aw[s][c] = *(const bf16x8*)&As[(wave * 32 + s * 16 + l16) * P + c * 32 + quad * 8];
#pragma unroll
        for (int nt = 0; nt < 4; ++nt)
#pragma unroll
            for (int c = 0; c < 2; ++c)
                bw[nt][c] = *(const bf16x8*)&Bs[(nt * 16 + l16) * P + c * 32 + quad * 8];
#pragma unroll
        for (int s = 0; s < 2; ++s)
#pragma unroll
            for (int nt = 0; nt < 4; ++nt) {
                acc[s][nt] = MFMA16(aw[s][0], bw[nt][0], acc[s][nt]);
                acc[s][nt] = MFMA16(aw[s][1], bw[nt][1], acc[s][nt]);
            }
        __syncthreads();
    }
#pragma unroll
    for (int s = 0; s < 2; ++s)
#pragma unroll
        for (int nt = 0; nt < 4; ++nt) {
            const float bias = bo[bc + nt * 16 + l16];
#pragma unroll
            for (int reg = 0; reg < 4; ++reg)
                out[(size_t)(br + wave * 32 + s * 16 + quad * 4 + reg) * E_ + bc + nt * 16 + l16] =
                    acc[s][nt][reg] + bias;
        }
}

// ---------------------------------------------------------------------------
extern "C" void kernel_launch(void* const* d_in, const int* in_sizes, int n_in,
                              void* d_out, int out_size, void* d_ws, size_t ws_size,
                              hipStream_t stream)
{
    const float* keys    = (const float*)d_in[0];
    const float* queries = (const float*)d_in[1];
    // d_in[2] (values) is UNUSED by the reference: v = q @ Wv.T
    const int*   mask    = (const int*)d_in[3];
    const float* Wk      = (const float*)d_in[4];
    const float* Wq      = (const float*)d_in[5];
    const float* Wv      = (const float*)d_in[6];
    const float* Wo      = (const float*)d_in[7];
    const float* bo      = (const float*)d_in[8];
    float* out = (float*)d_out;

    // workspace (bf16): q, k, vT, attn = 8 MB each; Wo_bf 2 MB; maskf 16 KB
    ushort_t* qbf  = (ushort_t*)d_ws;
    ushort_t* kbf  = qbf + (size_t)ROWS_ * 64;
    ushort_t* vtbf = kbf + (size_t)ROWS_ * 64;
    ushort_t* abf  = vtbf + (size_t)ROWS_ * 64;
    ushort_t* wob  = abf + (size_t)ROWS_ * 64;
    float*    mskf = (float*)(wob + (size_t)E_ * E_);

    conv_misc_kernel<<<1024 + (N_ * L_ + 255) / 256, 256, 0, stream>>>(Wo, mask, wob, mskf);
    proj_kernel<<<N_ * H_ * (L_ / 64), 256, 0, stream>>>(keys, queries, Wk, Wq, Wv,
                                                         qbf, kbf, vtbf);
    attn_kernel<<<N_ * H_ * (L_ / 32), 64, 0, stream>>>(qbf, kbf, vtbf, mskf, abf);
    outproj_kernel<<<(N_ * L_ / 128) * (E_ / 64), 256, 0, stream>>>(abf, wob, bo, out);
}

// Round 5
// 199.331 us; speedup vs baseline: 1.3023x; 1.3023x over previous
//
#include <hip/hip_runtime.h>
#include <cmath>

constexpr int N_ = 2;
constexpr int L_ = 2048;
constexpr int H_ = 16;
constexpr int E_ = 1024;
constexpr int ROWS_ = N_ * L_ * H_;   // 65536 token-head rows

typedef __attribute__((ext_vector_type(8))) short bf16x8;
typedef __attribute__((ext_vector_type(4))) float f32x4;
typedef unsigned short ushort_t;
#define MFMA16(a, b, c) __builtin_amdgcn_mfma_f32_16x16x32_bf16(a, b, c, 0, 0, 0)

__device__ __forceinline__ unsigned short f2bf(float x) {
    union { float f; unsigned u; } v; v.f = x;
    return (unsigned short)((v.u + 0x7fffu + ((v.u >> 16) & 1u)) >> 16);   // RNE
}
__device__ __forceinline__ unsigned pack2(float a, float b) {
    return (unsigned)f2bf(a) | ((unsigned)f2bf(b) << 16);
}

// ---------------------------------------------------------------------------
// Kernel 1: per-head projections, bf16 MFMA (unchanged — R3-verified).
// Emits q,k row-major [n][l][h][d]; v TRANSPOSED [n][h][d][l].
// ---------------------------------------------------------------------------
__global__ __launch_bounds__(256) void proj_kernel(
    const float* __restrict__ keys, const float* __restrict__ queries,
    const float* __restrict__ Wk, const float* __restrict__ Wq, const float* __restrict__ Wv,
    ushort_t* __restrict__ qo, ushort_t* __restrict__ ko, ushort_t* __restrict__ vto)
{
    constexpr int P = 72;
    __shared__ __align__(16) ushort_t Xq[64 * P];
    __shared__ __align__(16) ushort_t Xk[64 * P];
    __shared__ __align__(16) ushort_t Wqs[64 * P];
    __shared__ __align__(16) ushort_t Wks[64 * P];
    __shared__ __align__(16) ushort_t Wvs[64 * P];
    const int tid = threadIdx.x;
    const int lt = blockIdx.x & 31;
    const int h  = (blockIdx.x >> 5) & 15;
    const int n  = blockIdx.x >> 9;
    const int r0 = tid >> 4, c4 = (tid & 15) * 4;

#pragma unroll
    for (int j = 0; j < 4; ++j) {
        const int r = r0 + 16 * j;
        const size_t xoff = (size_t)(n * L_ + lt * 64 + r) * E_ + h * 64 + c4;
        const float4 xq = *(const float4*)&queries[xoff];
        const float4 xk = *(const float4*)&keys[xoff];
        const float4 wq = *(const float4*)&Wq[r * 64 + c4];
        const float4 wk = *(const float4*)&Wk[r * 64 + c4];
        const float4 wv = *(const float4*)&Wv[r * 64 + c4];
        *(uint2*)&Xq[r * P + c4]  = make_uint2(pack2(xq.x, xq.y), pack2(xq.z, xq.w));
        *(uint2*)&Xk[r * P + c4]  = make_uint2(pack2(xk.x, xk.y), pack2(xk.z, xk.w));
        *(uint2*)&Wqs[r * P + c4] = make_uint2(pack2(wq.x, wq.y), pack2(wq.z, wq.w));
        *(uint2*)&Wks[r * P + c4] = make_uint2(pack2(wk.x, wk.y), pack2(wk.z, wk.w));
        *(uint2*)&Wvs[r * P + c4] = make_uint2(pack2(wv.x, wv.y), pack2(wv.z, wv.w));
    }
    __syncthreads();

    const int wave = tid >> 6, lane = tid & 63;
    const int quad = lane >> 4, l16 = lane & 15;
    const int arow = (wave * 16 + l16) * P;
    const f32x4 zero = (f32x4){0.f, 0.f, 0.f, 0.f};

    bf16x8 a0 = *(const bf16x8*)&Xq[arow + quad * 8];
    bf16x8 a1 = *(const bf16x8*)&Xq[arow + 32 + quad * 8];
    bf16x8 c0 = *(const bf16x8*)&Xk[arow + quad * 8];
    bf16x8 c1 = *(const bf16x8*)&Xk[arow + 32 + quad * 8];
    f32x4 qf[4], kf[4];
#pragma unroll
    for (int nt = 0; nt < 4; ++nt) {
        const int brow = (nt * 16 + l16) * P;
        f32x4 acc = MFMA16(a0, *(const bf16x8*)&Wqs[brow + quad * 8], zero);
        qf[nt] = MFMA16(a1, *(const bf16x8*)&Wqs[brow + 32 + quad * 8], acc);
        acc = MFMA16(c0, *(const bf16x8*)&Wks[brow + quad * 8], zero);
        kf[nt] = MFMA16(c1, *(const bf16x8*)&Wks[brow + 32 + quad * 8], acc);
    }
    __syncthreads();

    const int crow = wave * 16 + quad * 4;
#pragma unroll
    for (int nt = 0; nt < 4; ++nt)
#pragma unroll
        for (int reg = 0; reg < 4; ++reg) {
            Xq[(crow + reg) * P + nt * 16 + l16]  = f2bf(qf[nt][reg]);
            Wqs[(crow + reg) * P + nt * 16 + l16] = f2bf(kf[nt][reg]);
        }
    asm volatile("s_waitcnt lgkmcnt(0)" ::: "memory");

    bf16x8 va0 = *(const bf16x8*)&Xq[arow + quad * 8];
    bf16x8 va1 = *(const bf16x8*)&Xq[arow + 32 + quad * 8];
    f32x4 vf[4];
#pragma unroll
    for (int nt = 0; nt < 4; ++nt) {
        const int brow = (nt * 16 + l16) * P;
        f32x4 acc = MFMA16(va0, *(const bf16x8*)&Wvs[brow + quad * 8], zero);
        vf[nt] = MFMA16(va1, *(const bf16x8*)&Wvs[brow + 32 + quad * 8], acc);
    }
#pragma unroll
    for (int nt = 0; nt < 4; ++nt)
#pragma unroll
        for (int reg = 0; reg < 4; ++reg)
            Xk[(nt * 16 + l16) * P + crow + reg] = f2bf(vf[nt][reg]);
    __syncthreads();

#pragma unroll
    for (int j = 0; j < 4; ++j) {
        const int r = r0 + 16 * j;
        const size_t qkoff = (size_t)(n * L_ + lt * 64 + r) * E_ + h * 64 + c4;
        *(uint2*)&qo[qkoff] = *(const uint2*)&Xq[r * P + c4];
        *(uint2*)&ko[qkoff] = *(const uint2*)&Wqs[r * P + c4];
        const size_t vtoff = ((size_t)(n * H_ + h) * 64 + r) * L_ + lt * 64 + c4;
        *(uint2*)&vto[vtoff] = *(const uint2*)&Xk[r * P + c4];
    }
}

// ---------------------------------------------------------------------------
// Kernel 2: MFMA flash attention, R3 staging structure + 2-strip waves.
// Block = 4 waves x 32 q-rows = 128 q-rows; K/V LDS tiles staged per block,
// fragment reads shared across both strips (S^T = K*Q^T: A=K strip-invariant,
// B=Q hoisted in regs). Mask enters as MFMA C-init (0/-1e9) -> p =
// exp2(s*log2e/32), exact 0 for masked keys. P written packed b64 ([q][key]).
// XCD swizzle: each XCD serves 4 heads -> K/V set 2 MB < 4 MB L2.
// ---------------------------------------------------------------------------
__global__ __launch_bounds__(256) void attn_kernel(
    const ushort_t* __restrict__ q, const ushort_t* __restrict__ k,
    const ushort_t* __restrict__ vt, const float* __restrict__ maskf,
    ushort_t* __restrict__ attn)
{
    constexpr int P = 72;
    constexpr float CEXP = 0.04508422002778010648f;   // log2(e)/32
    __shared__ __align__(16) ushort_t Ks[64 * P];
    __shared__ __align__(16) ushort_t VTs[64 * P];
    __shared__ __align__(16) ushort_t Ps[128 * P];
    __shared__ float Ls[128];

    // XCD-aware decode: xcd = g&7 gets heads [4*xcd, 4*xcd+4)
    const int g = blockIdx.x;
    const int xcd = g & 7, j0 = g >> 3;
    const int nh = xcd * 4 + (j0 & 3);
    const int qt = j0 >> 2;                // 0..15 (tiles of 128 rows)
    const int n = nh >> 4, h = nh & 15;

    const int tid = threadIdx.x;
    const int wave = tid >> 6, lane = tid & 63;
    const int l16 = lane & 15, quad = lane >> 4;
    const int r0 = tid >> 4, c4 = (tid & 15) * 4;

    const ushort_t* kh = k  + (size_t)n * L_ * E_ + h * 64;      // + key*E_ + d
    const ushort_t* vh = vt + (size_t)(n * H_ + h) * 64 * L_;    // + d*L_ + key
    const float*    mh = maskf + n * L_;
    const size_t qrow0 = (size_t)n * L_ + qt * 128 + wave * 32;

    // hoisted Q B-frags [strip][chain] (t-invariant)
    bf16x8 qb[2][2];
#pragma unroll
    for (int s = 0; s < 2; ++s)
#pragma unroll
        for (int c = 0; c < 2; ++c)
            qb[s][c] = *(const bf16x8*)&q[(qrow0 + s * 16 + l16) * E_ + h * 64 + c * 32 + quad * 8];

    // tile-0 staging prefetch + mask C-init prefetch
    uint2 kr[4], vr[4];
#pragma unroll
    for (int j = 0; j < 4; ++j) {
        const int r = r0 + 16 * j;
        kr[j] = *(const uint2*)&kh[(size_t)r * E_ + c4];
        vr[j] = *(const uint2*)&vh[(size_t)r * L_ + c4];
    }
    f32x4 mf[4];
#pragma unroll
    for (int mk = 0; mk < 4; ++mk) mf[mk] = *(const f32x4*)&mh[mk * 16 + quad * 4];

    float lacc[2] = {0.f, 0.f};
    f32x4 O[2][4];
#pragma unroll
    for (int s = 0; s < 2; ++s)
#pragma unroll
        for (int dt = 0; dt < 4; ++dt) O[s][dt] = (f32x4){0.f, 0.f, 0.f, 0.f};

    for (int t = 0; t < 32; ++t) {
        // commit staged tile
#pragma unroll
        for (int j = 0; j < 4; ++j) {
            const int r = r0 + 16 * j;
            *(uint2*)&Ks[r * P + c4]  = kr[j];
            *(uint2*)&VTs[r * P + c4] = vr[j];
        }
        __syncthreads();

        // prefetch t+1 (in flight during compute)
        const int tn = (t < 31) ? t + 1 : 31;
#pragma unroll
        for (int j = 0; j < 4; ++j) {
            const int r = r0 + 16 * j;
            kr[j] = *(const uint2*)&kh[(size_t)(tn * 64 + r) * E_ + c4];
            vr[j] = *(const uint2*)&vh[(size_t)r * L_ + tn * 64 + c4];
        }
        f32x4 mfn[4];
#pragma unroll
        for (int mk = 0; mk < 4; ++mk)
            mfn[mk] = *(const f32x4*)&mh[tn * 64 + mk * 16 + quad * 4];

        // K A-frags (strip-invariant)
        bf16x8 kA[4][2];
#pragma unroll
        for (int mk = 0; mk < 4; ++mk)
#pragma unroll
            for (int c = 0; c < 2; ++c)
                kA[mk][c] = *(const bf16x8*)&Ks[(mk * 16 + l16) * P + c * 32 + quad * 8];

        // S^T = K*Q^T + mask_init : C[key=16mk+quad*4+reg][q=l16]
        f32x4 sA[2][4];
#pragma unroll
        for (int s = 0; s < 2; ++s)
#pragma unroll
            for (int mk = 0; mk < 4; ++mk) {
                f32x4 acc = mf[mk];
                acc = MFMA16(kA[mk][0], qb[s][0], acc);
                sA[s][mk] = MFMA16(kA[mk][1], qb[s][1], acc);
            }

        // p = exp2(s*CEXP); packed b64 writes into P[q][key]
#pragma unroll
        for (int s = 0; s < 2; ++s)
#pragma unroll
            for (int mk = 0; mk < 4; ++mk) {
                const float p0 = __builtin_amdgcn_exp2f(sA[s][mk][0] * CEXP);
                const float p1 = __builtin_amdgcn_exp2f(sA[s][mk][1] * CEXP);
                const float p2 = __builtin_amdgcn_exp2f(sA[s][mk][2] * CEXP);
                const float p3 = __builtin_amdgcn_exp2f(sA[s][mk][3] * CEXP);
                lacc[s] += (p0 + p1) + (p2 + p3);
                *(uint2*)&Ps[(wave * 32 + s * 16 + l16) * P + mk * 16 + quad * 4] =
                    make_uint2(pack2(p0, p1), pack2(p2, p3));
            }
        asm volatile("s_waitcnt lgkmcnt(0)" ::: "memory");   // wave-private P

        // O += P*V ; V B-frags strip-invariant
        bf16x8 vB[4][2];
#pragma unroll
        for (int dt = 0; dt < 4; ++dt)
#pragma unroll
            for (int c = 0; c < 2; ++c)
                vB[dt][c] = *(const bf16x8*)&VTs[(dt * 16 + l16) * P + c * 32 + quad * 8];
        bf16x8 pa[2][2];
#pragma unroll
        for (int s = 0; s < 2; ++s)
#pragma unroll
            for (int c = 0; c < 2; ++c)
                pa[s][c] = *(const bf16x8*)&Ps[(wave * 32 + s * 16 + l16) * P + c * 32 + quad * 8];
#pragma unroll
        for (int s = 0; s < 2; ++s)
#pragma unroll
            for (int dt = 0; dt < 4; ++dt) {
                O[s][dt] = MFMA16(pa[s][0], vB[dt][0], O[s][dt]);
                O[s][dt] = MFMA16(pa[s][1], vB[dt][1], O[s][dt]);
            }
#pragma unroll
        for (int mk = 0; mk < 4; ++mk) mf[mk] = mfn[mk];
        __syncthreads();   // protect Ks/VTs before next commit
    }

    // l reduction: lane's q = l16; sum partials across quads
#pragma unroll
    for (int s = 0; s < 2; ++s) {
        float v = lacc[s];
        v += __shfl_xor(v, 16);
        v += __shfl_xor(v, 32);
        if (quad == 0) Ls[wave * 32 + s * 16 + l16] = 1.f / v;
    }
    asm volatile("s_waitcnt lgkmcnt(0)" ::: "memory");   // wave-private Ls
    f32x4 linv[2];
#pragma unroll
    for (int s = 0; s < 2; ++s) linv[s] = *(const f32x4*)&Ls[wave * 32 + s * 16 + quad * 4];

#pragma unroll
    for (int s = 0; s < 2; ++s)
#pragma unroll
        for (int dt = 0; dt < 4; ++dt)
#pragma unroll
            for (int reg = 0; reg < 4; ++reg) {
                const size_t row = qrow0 + s * 16 + quad * 4 + reg;
                attn[row * E_ + h * 64 + dt * 16 + l16] = f2bf(O[s][dt][reg] * linv[s][reg]);
            }
}

// ---------------------------------------------------------------------------
// Kernel 3: Wo fp32 -> bf16, and mask -> maskf (0 / -1e9)
// ---------------------------------------------------------------------------
__global__ __launch_bounds__(256) void conv_misc_kernel(
    const float* __restrict__ Wo, const int* __restrict__ mask,
    ushort_t* __restrict__ Wob, float* __restrict__ maskf)
{
    if (blockIdx.x < 1024) {
        const int i = (blockIdx.x * 256 + threadIdx.x) * 4;
        const float4 w = *(const float4*)&Wo[i];
        *(uint2*)&Wob[i] = make_uint2(pack2(w.x, w.y), pack2(w.z, w.w));
    } else {
        const int j = (blockIdx.x - 1024) * 256 + threadIdx.x;
        if (j < N_ * L_) maskf[j] = mask[j] ? 0.f : -1e9f;
    }
}

// ---------------------------------------------------------------------------
// Kernel 4: out = attn(4096x1024) @ Wo^T + bo. 128x64 tiles, 2-strip waves.
// ---------------------------------------------------------------------------
__global__ __launch_bounds__(256) void outproj_kernel(
    const ushort_t* __restrict__ attn, const ushort_t* __restrict__ Wob,
    const float* __restrict__ bo, float* __restrict__ out)
{
    constexpr int P = 72;
    __shared__ __align__(16) ushort_t As[128 * P];
    __shared__ __align__(16) ushort_t Bs[64 * P];
    const int tid = threadIdx.x;
    const int bc = (blockIdx.x & 15) * 64;
    const int br = (blockIdx.x >> 4) * 128;
    const int r0 = tid >> 4, c4 = (tid & 15) * 4;
    const int wave = tid >> 6, lane = tid & 63;
    const int quad = lane >> 4, l16 = lane & 15;

    uint2 ar[8], brg[4];
#pragma unroll
    for (int j = 0; j < 8; ++j)
        ar[j] = *(const uint2*)&attn[(size_t)(br + r0 + 16 * j) * E_ + c4];
#pragma unroll
    for (int j = 0; j < 4; ++j)
        brg[j] = *(const uint2*)&Wob[(size_t)(bc + r0 + 16 * j) * E_ + c4];

    f32x4 acc[2][4];
#pragma unroll
    for (int s = 0; s < 2; ++s)
#pragma unroll
        for (int nt = 0; nt < 4; ++nt) acc[s][nt] = (f32x4){0.f, 0.f, 0.f, 0.f};

    for (int kt = 0; kt < 16; ++kt) {
#pragma unroll
        for (int j = 0; j < 8; ++j) *(uint2*)&As[(r0 + 16 * j) * P + c4] = ar[j];
#pragma unroll
        for (int j = 0; j < 4; ++j) *(uint2*)&Bs[(r0 + 16 * j) * P + c4] = brg[j];
        __syncthreads();
        const int knext = ((kt < 15) ? (kt + 1) : kt) * 64;
#pragma unroll
        for (int j = 0; j < 8; ++j)
            ar[j] = *(const uint2*)&attn[(size_t)(br + r0 + 16 * j) * E_ + knext + c4];
#pragma unroll
        for (int j = 0; j < 4; ++j)
            brg[j] = *(const uint2*)&Wob[(size_t)(bc + r0 + 16 * j) * E_ + knext + c4];

        bf16x8 aw[2][2], bw[4][2];
#pragma unroll
        for (int s = 0; s < 2; ++s)
#pragma unroll
            for (int c = 0; c < 2; ++c)
                aw[s][c] = *(const bf16x8*)&As[(wave * 32 + s * 16 + l16) * P + c * 32 + quad * 8];
#pragma unroll
        for (int nt = 0; nt < 4; ++nt)
#pragma unroll
            for (int c = 0; c < 2; ++c)
                bw[nt][c] = *(const bf16x8*)&Bs[(nt * 16 + l16) * P + c * 32 + quad * 8];
#pragma unroll
        for (int s = 0; s < 2; ++s)
#pragma unroll
            for (int nt = 0; nt < 4; ++nt) {
                acc[s][nt] = MFMA16(aw[s][0], bw[nt][0], acc[s][nt]);
                acc[s][nt] = MFMA16(aw[s][1], bw[nt][1], acc[s][nt]);
            }
        __syncthreads();
    }
#pragma unroll
    for (int s = 0; s < 2; ++s)
#pragma unroll
        for (int nt = 0; nt < 4; ++nt) {
            const float bias = bo[bc + nt * 16 + l16];
#pragma unroll
            for (int reg = 0; reg < 4; ++reg)
                out[(size_t)(br + wave * 32 + s * 16 + quad * 4 + reg) * E_ + bc + nt * 16 + l16] =
                    acc[s][nt][reg] + bias;
        }
}

// ---------------------------------------------------------------------------
extern "C" void kernel_launch(void* const* d_in, const int* in_sizes, int n_in,
                              void* d_out, int out_size, void* d_ws, size_t ws_size,
                              hipStream_t stream)
{
    const float* keys    = (const float*)d_in[0];
    const float* queries = (const float*)d_in[1];
    // d_in[2] (values) is UNUSED by the reference: v = q @ Wv.T
    const int*   mask    = (const int*)d_in[3];
    const float* Wk      = (const float*)d_in[4];
    const float* Wq      = (const float*)d_in[5];
    const float* Wv      = (const float*)d_in[6];
    const float* Wo      = (const float*)d_in[7];
    const float* bo      = (const float*)d_in[8];
    float* out = (float*)d_out;

    // workspace (bf16): q, k, vT, attn = 8 MB each; Wo_bf 2 MB; maskf 16 KB
    ushort_t* qbf  = (ushort_t*)d_ws;
    ushort_t* kbf  = qbf + (size_t)ROWS_ * 64;
    ushort_t* vtbf = kbf + (size_t)ROWS_ * 64;
    ushort_t* abf  = vtbf + (size_t)ROWS_ * 64;
    ushort_t* wob  = abf + (size_t)ROWS_ * 64;
    float*    mskf = (float*)(wob + (size_t)E_ * E_);

    conv_misc_kernel<<<1024 + (N_ * L_ + 255) / 256, 256, 0, stream>>>(Wo, mask, wob, mskf);
    proj_kernel<<<N_ * H_ * (L_ / 64), 256, 0, stream>>>(keys, queries, Wk, Wq, Wv,
                                                         qbf, kbf, vtbf);
    attn_kernel<<<N_ * H_ * (L_ / 128), 256, 0, stream>>>(qbf, kbf, vtbf, mskf, abf);
    outproj_kernel<<<(N_ * L_ / 128) * (E_ / 64), 256, 0, stream>>>(abf, wob, bo, out);
}

// Round 6
// 196.496 us; speedup vs baseline: 1.3210x; 1.0144x over previous
//
#include <hip/hip_runtime.h>
#include <hip/hip_bf16.h>
#include <cmath>

constexpr int N_ = 2;
constexpr int L_ = 2048;
constexpr int H_ = 16;
constexpr int E_ = 1024;
constexpr int ROWS_ = N_ * L_ * H_;   // 65536 token-head rows
constexpr float KSCALE = 0.04508422002778010648f;   // log2(e)/32, folded into k

typedef __attribute__((ext_vector_type(8))) short bf16x8;
typedef __attribute__((ext_vector_type(4))) float f32x4;
typedef unsigned short ushort_t;
#define MFMA16(a, b, c) __builtin_amdgcn_mfma_f32_16x16x32_bf16(a, b, c, 0, 0, 0)

__device__ __forceinline__ unsigned short f2bf(float x) {
    union { float f; unsigned u; } v; v.f = x;
    return (unsigned short)((v.u + 0x7fffu + ((v.u >> 16) & 1u)) >> 16);   // RNE
}
// HW-packed bf16 pair (v_cvt_pk_bf16_f32 on gfx950)
__device__ __forceinline__ unsigned pack2(float a, float b) {
    __hip_bfloat162 t = __float22bfloat162_rn(make_float2(a, b));
    union { __hip_bfloat162 h; unsigned u; } v; v.h = t;
    return v.u;
}

// ---------------------------------------------------------------------------
// Kernel 1: per-head projections, bf16 MFMA.
// Emits q row-major [n][l][h][d]; k row-major PRE-SCALED by log2(e)/32;
// v TRANSPOSED [n][h][d][l].
// ---------------------------------------------------------------------------
__global__ __launch_bounds__(256) void proj_kernel(
    const float* __restrict__ keys, const float* __restrict__ queries,
    const float* __restrict__ Wk, const float* __restrict__ Wq, const float* __restrict__ Wv,
    ushort_t* __restrict__ qo, ushort_t* __restrict__ ko, ushort_t* __restrict__ vto)
{
    constexpr int P = 72;
    __shared__ __align__(16) ushort_t Xq[64 * P];
    __shared__ __align__(16) ushort_t Xk[64 * P];
    __shared__ __align__(16) ushort_t Wqs[64 * P];
    __shared__ __align__(16) ushort_t Wks[64 * P];
    __shared__ __align__(16) ushort_t Wvs[64 * P];
    const int tid = threadIdx.x;
    const int lt = blockIdx.x & 31;
    const int h  = (blockIdx.x >> 5) & 15;
    const int n  = blockIdx.x >> 9;
    const int r0 = tid >> 4, c4 = (tid & 15) * 4;

#pragma unroll
    for (int j = 0; j < 4; ++j) {
        const int r = r0 + 16 * j;
        const size_t xoff = (size_t)(n * L_ + lt * 64 + r) * E_ + h * 64 + c4;
        const float4 xq = *(const float4*)&queries[xoff];
        const float4 xk = *(const float4*)&keys[xoff];
        const float4 wq = *(const float4*)&Wq[r * 64 + c4];
        const float4 wk = *(const float4*)&Wk[r * 64 + c4];
        const float4 wv = *(const float4*)&Wv[r * 64 + c4];
        *(uint2*)&Xq[r * P + c4]  = make_uint2(pack2(xq.x, xq.y), pack2(xq.z, xq.w));
        *(uint2*)&Xk[r * P + c4]  = make_uint2(pack2(xk.x, xk.y), pack2(xk.z, xk.w));
        *(uint2*)&Wqs[r * P + c4] = make_uint2(pack2(wq.x, wq.y), pack2(wq.z, wq.w));
        *(uint2*)&Wks[r * P + c4] = make_uint2(pack2(wk.x, wk.y), pack2(wk.z, wk.w));
        *(uint2*)&Wvs[r * P + c4] = make_uint2(pack2(wv.x, wv.y), pack2(wv.z, wv.w));
    }
    __syncthreads();

    const int wave = tid >> 6, lane = tid & 63;
    const int quad = lane >> 4, l16 = lane & 15;
    const int arow = (wave * 16 + l16) * P;
    const f32x4 zero = (f32x4){0.f, 0.f, 0.f, 0.f};

    bf16x8 a0 = *(const bf16x8*)&Xq[arow + quad * 8];
    bf16x8 a1 = *(const bf16x8*)&Xq[arow + 32 + quad * 8];
    bf16x8 c0 = *(const bf16x8*)&Xk[arow + quad * 8];
    bf16x8 c1 = *(const bf16x8*)&Xk[arow + 32 + quad * 8];
    f32x4 qf[4], kf[4];
#pragma unroll
    for (int nt = 0; nt < 4; ++nt) {
        const int brow = (nt * 16 + l16) * P;
        f32x4 acc = MFMA16(a0, *(const bf16x8*)&Wqs[brow + quad * 8], zero);
        qf[nt] = MFMA16(a1, *(const bf16x8*)&Wqs[brow + 32 + quad * 8], acc);
        acc = MFMA16(c0, *(const bf16x8*)&Wks[brow + quad * 8], zero);
        kf[nt] = MFMA16(c1, *(const bf16x8*)&Wks[brow + 32 + quad * 8], acc);
    }
    __syncthreads();

    const int crow = wave * 16 + quad * 4;
#pragma unroll
    for (int nt = 0; nt < 4; ++nt)
#pragma unroll
        for (int reg = 0; reg < 4; ++reg) {
            Xq[(crow + reg) * P + nt * 16 + l16]  = f2bf(qf[nt][reg]);
            Wqs[(crow + reg) * P + nt * 16 + l16] = f2bf(kf[nt][reg] * KSCALE);
        }
    asm volatile("s_waitcnt lgkmcnt(0)" ::: "memory");

    bf16x8 va0 = *(const bf16x8*)&Xq[arow + quad * 8];
    bf16x8 va1 = *(const bf16x8*)&Xq[arow + 32 + quad * 8];
    f32x4 vf[4];
#pragma unroll
    for (int nt = 0; nt < 4; ++nt) {
        const int brow = (nt * 16 + l16) * P;
        f32x4 acc = MFMA16(va0, *(const bf16x8*)&Wvs[brow + quad * 8], zero);
        vf[nt] = MFMA16(va1, *(const bf16x8*)&Wvs[brow + 32 + quad * 8], acc);
    }
#pragma unroll
    for (int nt = 0; nt < 4; ++nt)
#pragma unroll
        for (int reg = 0; reg < 4; ++reg)
            Xk[(nt * 16 + l16) * P + crow + reg] = f2bf(vf[nt][reg]);
    __syncthreads();

#pragma unroll
    for (int j = 0; j < 4; ++j) {
        const int r = r0 + 16 * j;
        const size_t qkoff = (size_t)(n * L_ + lt * 64 + r) * E_ + h * 64 + c4;
        *(uint2*)&qo[qkoff] = *(const uint2*)&Xq[r * P + c4];
        *(uint2*)&ko[qkoff] = *(const uint2*)&Wqs[r * P + c4];
        const size_t vtoff = ((size_t)(n * H_ + h) * 64 + r) * L_ + lt * 64 + c4;
        *(uint2*)&vto[vtoff] = *(const uint2*)&Xk[r * P + c4];
    }
}

// ---------------------------------------------------------------------------
// Kernel 2: MFMA flash attention, double-buffered K/V staging (ONE barrier
// per tile). Block = 4 waves x 32 q-rows = 128 q-rows. S^T = K*Q^T (A=K
// strip-invariant, B=Q hoisted). K pre-scaled -> p = exp2(s) directly; mask
// enters as MFMA C-init (0/-1e9) -> exact 0. P written packed b64.
// XCD swizzle: each XCD serves 4 heads (K/V set 2 MB < 4 MB L2).
// ---------------------------------------------------------------------------
__global__ __launch_bounds__(256) void attn_kernel(
    const ushort_t* __restrict__ q, const ushort_t* __restrict__ k,
    const ushort_t* __restrict__ vt, const float* __restrict__ maskf,
    ushort_t* __restrict__ attn)
{
    constexpr int P = 72;
    __shared__ __align__(16) ushort_t Ks[2][64 * P];
    __shared__ __align__(16) ushort_t VTs[2][64 * P];
    __shared__ __align__(16) ushort_t Ps[128 * P];
    __shared__ float Ls[128];

    // XCD-aware decode: xcd = g&7 gets heads [4*xcd, 4*xcd+4)
    const int g = blockIdx.x;
    const int xcd = g & 7, j0 = g >> 3;
    const int nh = xcd * 4 + (j0 & 3);
    const int qt = j0 >> 2;                // 0..15 (tiles of 128 rows)
    const int n = nh >> 4, h = nh & 15;

    const int tid = threadIdx.x;
    const int wave = tid >> 6, lane = tid & 63;
    const int l16 = lane & 15, quad = lane >> 4;
    const int r0 = tid >> 4, c4 = (tid & 15) * 4;

    const ushort_t* kh = k  + (size_t)n * L_ * E_ + h * 64;      // + key*E_ + d
    const ushort_t* vh = vt + (size_t)(n * H_ + h) * 64 * L_;    // + d*L_ + key
    const float*    mh = maskf + n * L_;
    const size_t qrow0 = (size_t)n * L_ + qt * 128 + wave * 32;

    // hoisted Q B-frags [strip][chain] (t-invariant)
    bf16x8 qb[2][2];
#pragma unroll
    for (int s = 0; s < 2; ++s)
#pragma unroll
        for (int c = 0; c < 2; ++c)
            qb[s][c] = *(const bf16x8*)&q[(qrow0 + s * 16 + l16) * E_ + h * 64 + c * 32 + quad * 8];

    // tile-0 staging prefetch + mask C-init prefetch
    uint2 kr[4], vr[4];
#pragma unroll
    for (int j = 0; j < 4; ++j) {
        const int r = r0 + 16 * j;
        kr[j] = *(const uint2*)&kh[(size_t)r * E_ + c4];
        vr[j] = *(const uint2*)&vh[(size_t)r * L_ + c4];
    }
    f32x4 mf[4];
#pragma unroll
    for (int mk = 0; mk < 4; ++mk) mf[mk] = *(const f32x4*)&mh[mk * 16 + quad * 4];

    // commit tile 0 into buffer 0
#pragma unroll
    for (int j = 0; j < 4; ++j) {
        const int r = r0 + 16 * j;
        *(uint2*)&Ks[0][r * P + c4]  = kr[j];
        *(uint2*)&VTs[0][r * P + c4] = vr[j];
    }
    __syncthreads();

    float lacc[2] = {0.f, 0.f};
    f32x4 O[2][4];
#pragma unroll
    for (int s = 0; s < 2; ++s)
#pragma unroll
        for (int dt = 0; dt < 4; ++dt) O[s][dt] = (f32x4){0.f, 0.f, 0.f, 0.f};

    for (int t = 0; t < 32; ++t) {
        const int cur = t & 1, nxt = cur ^ 1;
        const int tn = (t < 31) ? t + 1 : 31;

        // issue global prefetch for t+1 (lands in regs during compute)
#pragma unroll
        for (int j = 0; j < 4; ++j) {
            const int r = r0 + 16 * j;
            kr[j] = *(const uint2*)&kh[(size_t)(tn * 64 + r) * E_ + c4];
            vr[j] = *(const uint2*)&vh[(size_t)r * L_ + tn * 64 + c4];
        }
        f32x4 mfn[4];
#pragma unroll
        for (int mk = 0; mk < 4; ++mk)
            mfn[mk] = *(const f32x4*)&mh[tn * 64 + mk * 16 + quad * 4];

        // K A-frags (strip-invariant)
        bf16x8 kA[4][2];
#pragma unroll
        for (int mk = 0; mk < 4; ++mk)
#pragma unroll
            for (int c = 0; c < 2; ++c)
                kA[mk][c] = *(const bf16x8*)&Ks[cur][(mk * 16 + l16) * P + c * 32 + quad * 8];

        // S^T = K'*Q^T + mask_init : C[key=16mk+quad*4+reg][q=l16]
        f32x4 sA[2][4];
#pragma unroll
        for (int s = 0; s < 2; ++s)
#pragma unroll
            for (int mk = 0; mk < 4; ++mk) {
                f32x4 acc = mf[mk];
                acc = MFMA16(kA[mk][0], qb[s][0], acc);
                sA[s][mk] = MFMA16(kA[mk][1], qb[s][1], acc);
            }

        // p = exp2(s) (K pre-scaled); packed b64 writes into P[q][key]
#pragma unroll
        for (int s = 0; s < 2; ++s)
#pragma unroll
            for (int mk = 0; mk < 4; ++mk) {
                const float p0 = __builtin_amdgcn_exp2f(sA[s][mk][0]);
                const float p1 = __builtin_amdgcn_exp2f(sA[s][mk][1]);
                const float p2 = __builtin_amdgcn_exp2f(sA[s][mk][2]);
                const float p3 = __builtin_amdgcn_exp2f(sA[s][mk][3]);
                lacc[s] += (p0 + p1) + (p2 + p3);
                *(uint2*)&Ps[(wave * 32 + s * 16 + l16) * P + mk * 16 + quad * 4] =
                    make_uint2(pack2(p0, p1), pack2(p2, p3));
            }
        asm volatile("s_waitcnt lgkmcnt(0)" ::: "memory");   // wave-private P

        // O += P*V ; V B-frags strip-invariant
        bf16x8 vB[4][2];
#pragma unroll
        for (int dt = 0; dt < 4; ++dt)
#pragma unroll
            for (int c = 0; c < 2; ++c)
                vB[dt][c] = *(const bf16x8*)&VTs[cur][(dt * 16 + l16) * P + c * 32 + quad * 8];
        bf16x8 pa[2][2];
#pragma unroll
        for (int s = 0; s < 2; ++s)
#pragma unroll
            for (int c = 0; c < 2; ++c)
                pa[s][c] = *(const bf16x8*)&Ps[(wave * 32 + s * 16 + l16) * P + c * 32 + quad * 8];
#pragma unroll
        for (int s = 0; s < 2; ++s)
#pragma unroll
            for (int dt = 0; dt < 4; ++dt) {
                O[s][dt] = MFMA16(pa[s][0], vB[dt][0], O[s][dt]);
                O[s][dt] = MFMA16(pa[s][1], vB[dt][1], O[s][dt]);
            }

        // commit t+1 into the idle buffer; ONE barrier covers reads(cur)+writes(nxt)
#pragma unroll
        for (int j = 0; j < 4; ++j) {
            const int r = r0 + 16 * j;
            *(uint2*)&Ks[nxt][r * P + c4]  = kr[j];
            *(uint2*)&VTs[nxt][r * P + c4] = vr[j];
        }
#pragma unroll
        for (int mk = 0; mk < 4; ++mk) mf[mk] = mfn[mk];
        __syncthreads();
    }

    // l redistribution: lane's l is for q=l16; O rows are q=quad*4+reg
#pragma unroll
    for (int s = 0; s < 2; ++s) {
        float v = lacc[s];
        v += __shfl_xor(v, 16);
        v += __shfl_xor(v, 32);
        if (quad == 0) Ls[wave * 32 + s * 16 + l16] = 1.f / v;
    }
    asm volatile("s_waitcnt lgkmcnt(0)" ::: "memory");   // wave-private Ls
    f32x4 linv[2];
#pragma unroll
    for (int s = 0; s < 2; ++s) linv[s] = *(const f32x4*)&Ls[wave * 32 + s * 16 + quad * 4];

#pragma unroll
    for (int s = 0; s < 2; ++s)
#pragma unroll
        for (int dt = 0; dt < 4; ++dt)
#pragma unroll
            for (int reg = 0; reg < 4; ++reg) {
                const size_t row = qrow0 + s * 16 + quad * 4 + reg;
                attn[row * E_ + h * 64 + dt * 16 + l16] = f2bf(O[s][dt][reg] * linv[s][reg]);
            }
}

// ---------------------------------------------------------------------------
// Kernel 3: Wo fp32 -> bf16, and mask -> maskf (0 / -1e9)
// ---------------------------------------------------------------------------
__global__ __launch_bounds__(256) void conv_misc_kernel(
    const float* __restrict__ Wo, const int* __restrict__ mask,
    ushort_t* __restrict__ Wob, float* __restrict__ maskf)
{
    if (blockIdx.x < 1024) {
        const int i = (blockIdx.x * 256 + threadIdx.x) * 4;
        const float4 w = *(const float4*)&Wo[i];
        *(uint2*)&Wob[i] = make_uint2(pack2(w.x, w.y), pack2(w.z, w.w));
    } else {
        const int j = (blockIdx.x - 1024) * 256 + threadIdx.x;
        if (j < N_ * L_) maskf[j] = mask[j] ? 0.f : -1e9f;
    }
}

// ---------------------------------------------------------------------------
// Kernel 4: out = attn(4096x1024) @ Wo^T + bo. 128x64 tiles, 2-strip waves.
// ---------------------------------------------------------------------------
__global__ __launch_bounds__(256) void outproj_kernel(
    const ushort_t* __restrict__ attn, const ushort_t* __restrict__ Wob,
    const float* __restrict__ bo, float* __restrict__ out)
{
    constexpr int P = 72;
    __shared__ __align__(16) ushort_t As[128 * P];
    __shared__ __align__(16) ushort_t Bs[64 * P];
    const int tid = threadIdx.x;
    const int bc = (blockIdx.x & 15) * 64;
    const int br = (blockIdx.x >> 4) * 128;
    const int r0 = tid >> 4, c4 = (tid & 15) * 4;
    const int wave = tid >> 6, lane = tid & 63;
    const int quad = lane >> 4, l16 = lane & 15;

    uint2 ar[8], brg[4];
#pragma unroll
    for (int j = 0; j < 8; ++j)
        ar[j] = *(const uint2*)&attn[(size_t)(br + r0 + 16 * j) * E_ + c4];
#pragma unroll
    for (int j = 0; j < 4; ++j)
        brg[j] = *(const uint2*)&Wob[(size_t)(bc + r0 + 16 * j) * E_ + c4];

    f32x4 acc[2][4];
#pragma unroll
    for (int s = 0; s < 2; ++s)
#pragma unroll
        for (int nt = 0; nt < 4; ++nt) acc[s][nt] = (f32x4){0.f, 0.f, 0.f, 0.f};

    for (int kt = 0; kt < 16; ++kt) {
#pragma unroll
        for (int j = 0; j < 8; ++j) *(uint2*)&As[(r0 + 16 * j) * P + c4] = ar[j];
#pragma unroll
        for (int j = 0; j < 4; ++j) *(uint2*)&Bs[(r0 + 16 * j) * P + c4] = brg[j];
        __syncthreads();
        const int knext = ((kt < 15) ? (kt + 1) : kt) * 64;
#pragma unroll
        for (int j = 0; j < 8; ++j)
            ar[j] = *(const uint2*)&attn[(size_t)(br + r0 + 16 * j) * E_ + knext + c4];
#pragma unroll
        for (int j = 0; j < 4; ++j)
            brg[j] = *(const uint2*)&Wob[(size_t)(bc + r0 + 16 * j) * E_ + knext + c4];

        bf16x8 aw[2][2], bw[4][2];
#pragma unroll
        for (int s = 0; s < 2; ++s)
#pragma unroll
            for (int c = 0; c < 2; ++c)
                aw[s][c] = *(const bf16x8*)&As[(wave * 32 + s * 16 + l16) * P + c * 32 + quad * 8];
#pragma unroll
        for (int nt = 0; nt < 4; ++nt)
#pragma unroll
            for (int c = 0; c < 2; ++c)
                bw[nt][c] = *(const bf16x8*)&Bs[(nt * 16 + l16) * P + c * 32 + quad * 8];
#pragma unroll
        for (int s = 0; s < 2; ++s)
#pragma unroll
            for (int nt = 0; nt < 4; ++nt) {
                acc[s][nt] = MFMA16(aw[s][0], bw[nt][0], acc[s][nt]);
                acc[s][nt] = MFMA16(aw[s][1], bw[nt][1], acc[s][nt]);
            }
        __syncthreads();
    }
#pragma unroll
    for (int s = 0; s < 2; ++s)
#pragma unroll
        for (int nt = 0; nt < 4; ++nt) {
            const float bias = bo[bc + nt * 16 + l16];
#pragma unroll
            for (int reg = 0; reg < 4; ++reg)
                out[(size_t)(br + wave * 32 + s * 16 + quad * 4 + reg) * E_ + bc + nt * 16 + l16] =
                    acc[s][nt][reg] + bias;
        }
}

// ---------------------------------------------------------------------------
extern "C" void kernel_launch(void* const* d_in, const int* in_sizes, int n_in,
                              void* d_out, int out_size, void* d_ws, size_t ws_size,
                              hipStream_t stream)
{
    const float* keys    = (const float*)d_in[0];
    const float* queries = (const float*)d_in[1];
    // d_in[2] (values) is UNUSED by the reference: v = q @ Wv.T
    const int*   mask    = (const int*)d_in[3];
    const float* Wk      = (const float*)d_in[4];
    const float* Wq      = (const float*)d_in[5];
    const float* Wv      = (const float*)d_in[6];
    const float* Wo      = (const float*)d_in[7];
    const float* bo      = (const float*)d_in[8];
    float* out = (float*)d_out;

    // workspace (bf16): q, k, vT, attn = 8 MB each; Wo_bf 2 MB; maskf 16 KB
    ushort_t* qbf  = (ushort_t*)d_ws;
    ushort_t* kbf  = qbf + (size_t)ROWS_ * 64;
    ushort_t* vtbf = kbf + (size_t)ROWS_ * 64;
    ushort_t* abf  = vtbf + (size_t)ROWS_ * 64;
    ushort_t* wob  = abf + (size_t)ROWS_ * 64;
    float*    mskf = (float*)(wob + (size_t)E_ * E_);

    conv_misc_kernel<<<1024 + (N_ * L_ + 255) / 256, 256, 0, stream>>>(Wo, mask, wob, mskf);
    proj_kernel<<<N_ * H_ * (L_ / 64), 256, 0, stream>>>(keys, queries, Wk, Wq, Wv,
                                                         qbf, kbf, vtbf);
    attn_kernel<<<N_ * H_ * (L_ / 128), 256, 0, stream>>>(qbf, kbf, vtbf, mskf, abf);
    outproj_kernel<<<(N_ * L_ / 128) * (E_ / 64), 256, 0, stream>>>(abf, wob, bo, out);
}